// Round 25
// baseline (1432.310 us; speedup 1.0000x reference)
//
#include <hip/hip_runtime.h>

#define LEN 21760
#define MROWS 43520
#define WSTRIDE 753664

typedef __attribute__((ext_vector_type(8))) short s8v;
typedef __attribute__((ext_vector_type(4))) short s4v;
typedef __attribute__((ext_vector_type(4))) float f4v;
typedef __attribute__((ext_vector_type(2))) float f2v;
typedef __attribute__((ext_vector_type(4))) unsigned u4v;

__device__ inline float bf2f(short u){
  union { unsigned u; float f; } v; v.u = ((unsigned)(unsigned short)u) << 16; return v.f;
}
__device__ inline short f2bf(float f){
  union { float f; unsigned u; } v; v.f = f;
  unsigned r = v.u + 0x7fffu + ((v.u >> 16) & 1u);
  return (short)(r >> 16);
}
__device__ inline void gload_lds16(const short* g, short* l){
  __builtin_amdgcn_global_load_lds((const __attribute__((address_space(1))) void*)g,
                                   (__attribute__((address_space(3))) void*)l, 16, 0, 0);
}

// Tiled NCHW -> NLC transpose: block = 64 positions x 256 channels.
__global__ __launch_bounds__(256) void prep_kernel(
    const float* __restrict__ s0,const float* __restrict__ s1,
    const float* __restrict__ s2,const float* __restrict__ s3,
    const float* __restrict__ p0,const float* __restrict__ p1,
    const float* __restrict__ p2,const float* __restrict__ p3,
    const float* __restrict__ le,
    short* __restrict__ xbf, short* __restrict__ posb,
    short* __restrict__ q)
{
  __shared__ float xs[64][65];
  __shared__ float ps[64][65];
  const int n0 = blockIdx.x * 64;
  const int b  = blockIdx.y;
  const int t  = threadIdx.x;

  int l, s0n, lw;
  if (n0 < 16384){ l=0; s0n=0; lw=7; }
  else if (n0 < 20480){ l=1; s0n=16384; lw=6; }
  else if (n0 < 21504){ l=2; s0n=20480; lw=5; }
  else { l=3; s0n=21504; lw=4; }
  const int pbase = n0 - s0n;
  const long HW = 1L << (2*lw);
  const float* sp = (l==0?s0:(l==1?s1:(l==2?s2:s3)));
  const float* pp = (l==0?p0:(l==1?p1:(l==2?p2:p3)));

  for (int ch0 = 0; ch0 < 256; ch0 += 64){
    __syncthreads();
    #pragma unroll
    for (int cc = 0; cc < 4; cc++){
      int cl = cc*16 + (t >> 4);
      int quad = t & 15;
      int ch = ch0 + cl;
      long gi = (long)(b*256 + ch)*HW + pbase + quad*4;
      f4v xv = *(const f4v*)&sp[gi];
      f4v pv = *(const f4v*)&pp[gi];
      float lec = le[l*256 + ch];
      *(f4v*)&xs[cl][quad*4] = xv;
      f4v pe; pe[0]=pv[0]+lec; pe[1]=pv[1]+lec; pe[2]=pv[2]+lec; pe[3]=pv[3]+lec;
      *(f4v*)&ps[cl][quad*4] = pe;
    }
    __syncthreads();
    #pragma unroll
    for (int cc = 0; cc < 4; cc++){
      int pi = t >> 2;
      int cl = cc*16 + (t & 3)*4;
      long row = (long)b*LEN + n0 + pi;
      int col = ch0 + cl;
      s4v xv, pv, qv;
      #pragma unroll
      for (int j=0;j<4;j++){
        float xf = xs[cl+j][pi];
        float pf = ps[cl+j][pi];
        xv[j] = f2bf(xf); pv[j] = f2bf(pf);
        qv[j] = f2bf(xf + pf);
      }
      *(s4v*)&xbf[row*256 + col]  = xv;
      *(s4v*)&posb[row*256 + col] = pv;
      *(s4v*)&q[row*256 + col]    = qv;
    }
  }
}

// LDS-tiled weight transpose+convert to bf16 [N][K] (64x64 tiles).
// Blocks [0,1104): transpose tiles; [1104,1110): biasOA copy per layer.
__global__ __launch_bounds__(256) void convw_kernel(
    const float* __restrict__ Woff, const float* __restrict__ Waw,
    const float* __restrict__ Wv, const float* __restrict__ Wout,
    const float* __restrict__ W1, const float* __restrict__ W2,
    const float* __restrict__ boff, const float* __restrict__ baw,
    short* __restrict__ wts, float* __restrict__ biasOA)
{
  const int id = blockIdx.x;
  if (id >= 1104){
    int li = id - 1104;
    for (int i = threadIdx.x; i < 384; i += 256)
      biasOA[li*384 + i] = (i < 256) ? boff[li*256 + i] : baw[li*128 + (i-256)];
    return;
  }
  __shared__ float ls[64][65];
  const int li = id / 184;
  int r = id % 184;
  const float* src; short* dst; int N, K;
  if (r < 16)      {          src=Woff+li*65536;  dst=wts+(size_t)li*WSTRIDE;        N=256;  K=256;  }
  else if (r < 24) { r-=16;   src=Waw +li*32768;  dst=wts+(size_t)li*WSTRIDE+65536;  N=128;  K=256;  }
  else if (r < 40) { r-=24;   src=Wv  +li*65536;  dst=wts+(size_t)li*WSTRIDE+98304;  N=256;  K=256;  }
  else if (r < 56) { r-=40;   src=Wout+li*65536;  dst=wts+(size_t)li*WSTRIDE+163840; N=256;  K=256;  }
  else if (r < 120){ r-=56;   src=W1  +li*262144; dst=wts+(size_t)li*WSTRIDE+229376; N=1024; K=256;  }
  else             { r-=120;  src=W2  +li*262144; dst=wts+(size_t)li*WSTRIDE+491520; N=256;  K=1024; }
  const int ntn = N >> 6;
  const int tn = r % ntn, tk = r / ntn;
  const int n0 = tn*64, k0 = tk*64;
  const int t = threadIdx.x;
  const int rr = t >> 4;
  const int c4 = (t & 15) * 4;
  #pragma unroll
  for (int it = 0; it < 4; it++){
    int row = it*16 + rr;
    f4v v = *(const f4v*)&src[(long)(k0+row)*N + n0 + c4];
    ls[row][c4] = v[0]; ls[row][c4+1] = v[1]; ls[row][c4+2] = v[2]; ls[row][c4+3] = v[3];
  }
  __syncthreads();
  #pragma unroll
  for (int it = 0; it < 4; it++){
    int nrow = it*16 + rr;
    s4v o;
    #pragma unroll
    for (int j=0;j<4;j++) o[j] = f2bf(ls[c4+j][nrow]);
    *(s4v*)&dst[(long)(n0+nrow)*K + k0 + c4] = o;
  }
}

// Generic GEMM: C[M,N] = A*Wt^T + bias (+relu) -> f32 or bf16.
// 1-D grid, bijective XCD chunking. EMIT_Q: also q = bf16(v+pos_bf16).
template<bool RELU, bool OUT_BF16, bool EMIT_Q>
__global__ __launch_bounds__(256) void gemm_bf16(
    const short* __restrict__ A, const short* __restrict__ Wt,
    const float* __restrict__ bias,
    void* __restrict__ Cout, const short* __restrict__ posb,
    short* __restrict__ qout,
    int M, int N, int K, int NT)
{
  __shared__ short As[128*64];
  __shared__ short Bs[128*64];
  const int p = blockIdx.x, nwg = gridDim.x;
  const int xq = nwg >> 3, xr = nwg & 7;
  const int xx = p & 7, xs2 = p >> 3;
  const int l = ((xx < xr) ? xx*(xq+1) : xr*(xq+1) + (xx-xr)*xq) + xs2;
  const int m0 = (l / NT) * 128;
  const int n0 = (l % NT) * 128;

  const int t = threadIdx.x;
  const int lane = t & 63, wv = t >> 6;
  const int wm = (wv >> 1) * 64, wn = (wv & 1) * 64;
  const int fr = lane & 15, fg = lane >> 4;
  const int srow = lane >> 3;
  const int schunk = (lane & 7) ^ (srow & 7);

  f4v acc[4][4];
  #pragma unroll
  for (int i=0;i<4;i++)
    #pragma unroll
    for (int j=0;j<4;j++) acc[i][j] = (f4v){0.f,0.f,0.f,0.f};

  for (int k0 = 0; k0 < K; k0 += 64) {
    __syncthreads();
    #pragma unroll
    for (int i=0;i<4;i++){
      int seg = wv*4 + i;
      int row = seg*8 + srow;
      gload_lds16(&A [(long)(m0+row)*K + k0 + schunk*8], &As[seg*512]);
      gload_lds16(&Wt[(long)(n0+row)*K + k0 + schunk*8], &Bs[seg*512]);
    }
    __syncthreads();
    #pragma unroll
    for (int kk=0; kk<64; kk+=32){
      s8v ar[4], br[4];
      #pragma unroll
      for (int i=0;i<4;i++){
        int r = wm + i*16 + fr;
        int ch = ((kk>>3) + fg) ^ (fr & 7);
        ar[i] = *(const s8v*)&As[r*64 + ch*8];
      }
      #pragma unroll
      for (int j=0;j<4;j++){
        int r = wn + j*16 + fr;
        int ch = ((kk>>3) + fg) ^ (fr & 7);
        br[j] = *(const s8v*)&Bs[r*64 + ch*8];
      }
      #pragma unroll
      for (int i=0;i<4;i++)
        #pragma unroll
        for (int j=0;j<4;j++)
          acc[i][j] = __builtin_amdgcn_mfma_f32_16x16x32_bf16(ar[i], br[j], acc[i][j], 0,0,0);
    }
  }
  #pragma unroll
  for (int i=0;i<4;i++){
    #pragma unroll
    for (int j=0;j<4;j++){
      int col = n0 + wn + j*16 + fr;
      float bcol = bias[col];
      #pragma unroll
      for (int r=0;r<4;r++){
        long row = m0 + wm + i*16 + fg*4 + r;
        float vv = acc[i][j][r] + bcol;
        if (RELU) vv = fmaxf(vv, 0.f);
        if (OUT_BF16) ((short*)Cout)[row*N + col] = f2bf(vv);
        else ((float*)Cout)[row*N + col] = vv;
        if (EMIT_Q){
          qout[row*N + col] = f2bf(vv + bf2f(posb[row*N + col]));
        }
      }
    }
  }
}

// Fused out-proj + residual(bf16) + LayerNorm. Tile 128 rows x 256 cols.
__global__ __launch_bounds__(512) void gemm_out_ln(
    const short* __restrict__ A, const short* __restrict__ Wt,
    const float* __restrict__ bias, const short* __restrict__ resid,
    const float* __restrict__ gamma, const float* __restrict__ beta,
    short* __restrict__ xln)
{
  const int K = 256;
  __shared__ short As[128*64];
  __shared__ short Bs[256*64];
  const int m0 = blockIdx.x * 128;
  const int t = threadIdx.x;
  const int lane = t & 63, wv = t >> 6;       // 8 waves
  const int wm = wv * 16;
  const int fr = lane & 15, fg = lane >> 4;
  const int srow = lane >> 3;
  const int schunk = (lane & 7) ^ (srow & 7);

  f4v acc[16];
  #pragma unroll
  for (int j=0;j<16;j++) acc[j] = (f4v){0.f,0.f,0.f,0.f};

  for (int k0 = 0; k0 < K; k0 += 64) {
    __syncthreads();
    #pragma unroll
    for (int i=0;i<2;i++){
      int seg = wv*2 + i;
      int row = seg*8 + srow;
      gload_lds16(&A[(long)(m0+row)*K + k0 + schunk*8], &As[seg*512]);
    }
    #pragma unroll
    for (int i=0;i<4;i++){
      int seg = wv*4 + i;
      int row = seg*8 + srow;
      gload_lds16(&Wt[(long)row*K + k0 + schunk*8], &Bs[seg*512]);
    }
    __syncthreads();
    #pragma unroll
    for (int kk=0; kk<64; kk+=32){
      int ch = ((kk>>3) + fg);
      s8v ar = *(const s8v*)&As[(wm + fr)*64 + ((ch ^ (fr & 7)))*8];
      #pragma unroll
      for (int j=0;j<16;j++){
        s8v br = *(const s8v*)&Bs[(j*16 + fr)*64 + ((ch ^ (fr & 7)))*8];
        acc[j] = __builtin_amdgcn_mfma_f32_16x16x32_bf16(ar, br, acc[j], 0,0,0);
      }
    }
  }
  #pragma unroll
  for (int r=0;r<4;r++){
    long row = m0 + wm + fg*4 + r;
    float vals[16];
    float s = 0.f;
    #pragma unroll
    for (int j=0;j<16;j++){
      int col = j*16 + fr;
      float vv = acc[j][r] + bias[col] + bf2f(resid[row*256 + col]);
      vals[j] = vv; s += vv;
    }
    #pragma unroll
    for (int o=1;o<16;o<<=1) s += __shfl_xor(s, o, 64);
    float mu = s * (1.f/256.f);
    float s2 = 0.f;
    #pragma unroll
    for (int j=0;j<16;j++){ float d = vals[j]-mu; vals[j] = d; s2 += d*d; }
    #pragma unroll
    for (int o=1;o<16;o<<=1) s2 += __shfl_xor(s2, o, 64);
    float rstd = rsqrtf(s2*(1.f/256.f) + 1e-5f);
    #pragma unroll
    for (int j=0;j<16;j++){
      int col = j*16 + fr;
      xln[row*256 + col] = f2bf(vals[j]*rstd*gamma[col] + beta[col]);
    }
  }
}

// Deformable sampling — r23 form + packed float2 accumulation (v_pk_fma_f32):
// each gathered u32 = (lo,hi) bf16 pair sharing one weight -> f2v FMA halves
// the FMA issue count (32 -> 16 pk-ops per point). Same math, same VGPRs.
__global__ __launch_bounds__(256) void sample_kernel(const short* __restrict__ v,
                const short* __restrict__ offaw, short* __restrict__ accO)
{
  const int t = threadIdx.x;
  const int qi = t >> 5;
  const int tq = t & 31;
  const int head = tq >> 2, cg = tq & 3;
  const int bid = blockIdx.x;
  const int n = ((bid & 7) * 340 + (bid >> 3)) * 8 + qi;   // XCD swizzle
  const int b = blockIdx.y;
  const long m = (long)b*LEN + n;
  const short* oa = offaw + m*384;

  s8v or0 = *(const s8v*)&oa[head*32];
  s8v or1 = *(const s8v*)&oa[head*32 + 8];
  s8v or2 = *(const s8v*)&oa[head*32 + 16];
  s8v or3 = *(const s8v*)&oa[head*32 + 24];
  float off_f[32];
  #pragma unroll
  for (int i=0;i<8;i++){
    off_f[i]    = bf2f(or0[i]);
    off_f[8+i]  = bf2f(or1[i]);
    off_f[16+i] = bf2f(or2[i]);
    off_f[24+i] = bf2f(or3[i]);
  }

  s8v lg0 = *(const s8v*)&oa[256 + head*16];
  s8v lg1 = *(const s8v*)&oa[256 + head*16 + 8];
  float logit[16];
  #pragma unroll
  for (int i=0;i<8;i++){ logit[i] = bf2f(lg0[i]); logit[8+i] = bf2f(lg1[i]); }
  float mx = -1e30f;
  #pragma unroll
  for (int j=0;j<16;j++) mx = fmaxf(mx, logit[j]);
  float ssum = 0.f;
  #pragma unroll
  for (int j=0;j<16;j++){ logit[j] = __expf(logit[j]-mx); ssum += logit[j]; }
  float inv = 1.f/ssum;

  int s0n, lwn;
  if (n < 16384){ s0n=0; lwn=7; }
  else if (n < 20480){ s0n=16384; lwn=6; }
  else if (n < 21504){ s0n=20480; lwn=5; }
  else { s0n=21504; lwn=4; }
  int p = n - s0n;
  int Wn = 1 << lwn;
  float refx = ((p & (Wn-1)) + 0.5f) / Wn;
  float refy = ((p >> lwn) + 0.5f) / Wn;

  const int starts[4] = {0,16384,20480,21504};
  f2v acc2[4];
  #pragma unroll
  for (int c=0;c<4;c++) acc2[c] = (f2v){0.f, 0.f};

  #pragma unroll
  for (int l=0;l<4;l++){
    const int W = 128 >> l, Wm1 = W - 1;
    const short* vb = v + ((long)b*LEN + starts[l])*256 + head*32 + cg*8;
    #pragma unroll
    for (int pp=0;pp<4;pp++){
      int j = l*4 + pp;
      float sx = refx * W + off_f[j*2]     - 0.5f;
      float sy = refy * W + off_f[j*2 + 1] - 0.5f;
      float fx0 = floorf(sx), fy0 = floorf(sy);
      float dx = sx - fx0, dy = sy - fy0;
      int x0 = (int)fx0, y0 = (int)fy0;
      int x0c = min(max(x0,0),Wm1),   x1c = min(max(x0+1,0),Wm1);
      int y0c = min(max(y0,0),Wm1),   y1c = min(max(y0+1,0),Wm1);
      float aw = logit[j] * inv;
      float r0w = ((unsigned)y0     < (unsigned)W) ? (1.f-dy)*aw : 0.f;
      float r1w = ((unsigned)(y0+1) < (unsigned)W) ? dy*aw       : 0.f;
      float c0w = ((unsigned)x0     < (unsigned)W) ? (1.f-dx)    : 0.f;
      float c1w = ((unsigned)(x0+1) < (unsigned)W) ? dx          : 0.f;
      float w00 = r0w*c0w, w10 = r0w*c1w, w01 = r1w*c0w, w11 = r1w*c1w;
      const short* r0p = vb + (long)(y0c*W)*256;
      const short* r1p = vb + (long)(y1c*W)*256;
      u4v g00 = *(const u4v*)&r0p[x0c*256];
      u4v g10 = *(const u4v*)&r0p[x1c*256];
      u4v g01 = *(const u4v*)&r1p[x0c*256];
      u4v g11 = *(const u4v*)&r1p[x1c*256];
      #pragma unroll
      for (int c=0;c<4;c++){
        union {unsigned u; float f;} l00,h00,l10,h10,l01,h01,l11,h11;
        l00.u = g00[c] << 16;  h00.u = g00[c];
        l10.u = g10[c] << 16;  h10.u = g10[c];
        l01.u = g01[c] << 16;  h01.u = g01[c];
        l11.u = g11[c] << 16;  h11.u = g11[c];
        f2v p00 = (f2v){l00.f, h00.f};
        f2v p10 = (f2v){l10.f, h10.f};
        f2v p01 = (f2v){l01.f, h01.f};
        f2v p11 = (f2v){l11.f, h11.f};
        acc2[c] = acc2[c] + w00*p00 + w10*p10 + w01*p01 + w11*p11;
      }
    }
  }
  s8v o;
  #pragma unroll
  for (int c=0;c<4;c++){ o[2*c] = f2bf(acc2[c][0]); o[2*c+1] = f2bf(acc2[c][1]); }
  *(s8v*)&accO[m*256 + head*32 + cg*8] = o;
}

extern "C" void kernel_launch(void* const* d_in, const int* in_sizes, int n_in,
                              void* d_out, int out_size, void* d_ws, size_t ws_size,
                              hipStream_t stream)
{
  const float* s0   = (const float*)d_in[0];
  const float* p0   = (const float*)d_in[1];
  const float* s1   = (const float*)d_in[2];
  const float* p1   = (const float*)d_in[3];
  const float* s2   = (const float*)d_in[4];
  const float* p2   = (const float*)d_in[5];
  const float* s3   = (const float*)d_in[6];
  const float* p3   = (const float*)d_in[7];
  const float* le   = (const float*)d_in[8];
  const float* Wv   = (const float*)d_in[9];
  const float* bv   = (const float*)d_in[10];
  const float* Woff = (const float*)d_in[11];
  const float* boff = (const float*)d_in[12];
  const float* Waw  = (const float*)d_in[13];
  const float* baw  = (const float*)d_in[14];
  const float* Wout = (const float*)d_in[15];
  const float* bout = (const float*)d_in[16];
  const float* gamma= (const float*)d_in[17];
  const float* beta = (const float*)d_in[18];
  const float* W1   = (const float*)d_in[19];
  const float* b1   = (const float*)d_in[20];
  const float* W2   = (const float*)d_in[21];
  const float* b2   = (const float*)d_in[22];

  char* wsb = (char*)d_ws;
  short* xbf   = (short*)(wsb);                // 22,282,240 (bf16 residual stream)
  short* posb  = (short*)(wsb + 22282240);     // 22,282,240 (bf16 pos)
  short* qxln  = (short*)(wsb + 44564480);     // 22,282,240 (q | xln)
  // scratch region R (89,128,960 B): attention {vbf, accb, offaw} | FFN {h}
  short* vbf   = (short*)(wsb + 66846720);     // 22,282,240
  short* accb  = (short*)(wsb + 89128960);     // 22,282,240
  short* offawh= (short*)(wsb + 111411200);    // 33,423,360 used (offaw)
  short* hbuf  = (short*)(wsb + 66846720);     // 89,128,960 (FFN hidden, aliases above)
  short* wts   = (short*)(wsb + 155975680);    // 9,043,968
  float* biasOA= (float*)(wsb + 165019648);    // 9,216

  prep_kernel<<<dim3(340,2),256,0,stream>>>(s0,s1,s2,s3,p0,p1,p2,p3,le,xbf,posb,qxln);
  convw_kernel<<<1110,256,0,stream>>>(Woff,Waw,Wv,Wout,W1,W2,boff,baw,wts,biasOA);

  for (int li = 0; li < 6; li++){
    const short* wl = wts + (size_t)li*WSTRIDE;
    // offsets + attention logits: [M,384]  (reads q in qxln); 340x3 tiles
    gemm_bf16<false,true,false><<<1020,256,0,stream>>>(
        qxln, wl, biasOA+li*384, offawh, nullptr,nullptr, MROWS, 384, 256, 3);
    // values: [M,256] bf16  (reads residual stream xbf); 340x2 tiles
    gemm_bf16<false,true,false><<<680,256,0,stream>>>(
        xbf, wl+98304, bv+li*256, vbf, nullptr,nullptr, MROWS, 256, 256, 2);
    // deformable sampling -> accb
    sample_kernel<<<dim3(LEN/8,2),256,0,stream>>>(vbf, offawh, accb);
    // fused out-proj + residual(bf16 xbf) + LN -> xln (qxln)
    gemm_out_ln<<<340,512,0,stream>>>(accb, wl+163840, bout+li*256, xbf,
                                      gamma+li*256, beta+li*256, qxln);
    // FFN, unchunked: FFN1 writes h (aliases dead vbf/accb/offaw), FFN2 -> xbf+q
    gemm_bf16<true,true,false><<<2720,256,0,stream>>>(
        qxln, wl+229376, b1+li*1024, hbuf, nullptr,nullptr, MROWS, 1024, 256, 8);
    if (li < 5){
      gemm_bf16<false,true,true><<<680,256,0,stream>>>(
          hbuf, wl+491520, b2+li*256, xbf, posb, qxln, MROWS, 256, 1024, 2);
    } else {
      gemm_bf16<false,false,false><<<680,256,0,stream>>>(
          hbuf, wl+491520, b2+li*256, (float*)d_out, nullptr,nullptr, MROWS, 256, 1024, 2);
    }
  }
}

// Round 26
// 1407.189 us; speedup vs baseline: 1.0179x; 1.0179x over previous
//
#include <hip/hip_runtime.h>

#define LEN 21760
#define MROWS 43520
#define WSTRIDE 753664

typedef __attribute__((ext_vector_type(8))) short s8v;
typedef __attribute__((ext_vector_type(4))) short s4v;
typedef __attribute__((ext_vector_type(4))) float f4v;
typedef __attribute__((ext_vector_type(4))) unsigned u4v;

__device__ inline float bf2f(short u){
  union { unsigned u; float f; } v; v.u = ((unsigned)(unsigned short)u) << 16; return v.f;
}
__device__ inline short f2bf(float f){
  union { float f; unsigned u; } v; v.f = f;
  unsigned r = v.u + 0x7fffu + ((v.u >> 16) & 1u);
  return (short)(r >> 16);
}
__device__ inline void gload_lds16(const short* g, short* l){
  __builtin_amdgcn_global_load_lds((const __attribute__((address_space(1))) void*)g,
                                   (__attribute__((address_space(3))) void*)l, 16, 0, 0);
}

// Tiled NCHW -> NLC transpose: block = 64 positions x 256 channels.
__global__ __launch_bounds__(256) void prep_kernel(
    const float* __restrict__ s0,const float* __restrict__ s1,
    const float* __restrict__ s2,const float* __restrict__ s3,
    const float* __restrict__ p0,const float* __restrict__ p1,
    const float* __restrict__ p2,const float* __restrict__ p3,
    const float* __restrict__ le,
    short* __restrict__ xbf, short* __restrict__ posb,
    short* __restrict__ q)
{
  __shared__ float xs[64][65];
  __shared__ float ps[64][65];
  const int n0 = blockIdx.x * 64;
  const int b  = blockIdx.y;
  const int t  = threadIdx.x;

  int l, s0n, lw;
  if (n0 < 16384){ l=0; s0n=0; lw=7; }
  else if (n0 < 20480){ l=1; s0n=16384; lw=6; }
  else if (n0 < 21504){ l=2; s0n=20480; lw=5; }
  else { l=3; s0n=21504; lw=4; }
  const int pbase = n0 - s0n;
  const long HW = 1L << (2*lw);
  const float* sp = (l==0?s0:(l==1?s1:(l==2?s2:s3)));
  const float* pp = (l==0?p0:(l==1?p1:(l==2?p2:p3)));

  for (int ch0 = 0; ch0 < 256; ch0 += 64){
    __syncthreads();
    #pragma unroll
    for (int cc = 0; cc < 4; cc++){
      int cl = cc*16 + (t >> 4);
      int quad = t & 15;
      int ch = ch0 + cl;
      long gi = (long)(b*256 + ch)*HW + pbase + quad*4;
      f4v xv = *(const f4v*)&sp[gi];
      f4v pv = *(const f4v*)&pp[gi];
      float lec = le[l*256 + ch];
      *(f4v*)&xs[cl][quad*4] = xv;
      f4v pe; pe[0]=pv[0]+lec; pe[1]=pv[1]+lec; pe[2]=pv[2]+lec; pe[3]=pv[3]+lec;
      *(f4v*)&ps[cl][quad*4] = pe;
    }
    __syncthreads();
    #pragma unroll
    for (int cc = 0; cc < 4; cc++){
      int pi = t >> 2;
      int cl = cc*16 + (t & 3)*4;
      long row = (long)b*LEN + n0 + pi;
      int col = ch0 + cl;
      s4v xv, pv, qv;
      #pragma unroll
      for (int j=0;j<4;j++){
        float xf = xs[cl+j][pi];
        float pf = ps[cl+j][pi];
        xv[j] = f2bf(xf); pv[j] = f2bf(pf);
        qv[j] = f2bf(xf + pf);
      }
      *(s4v*)&xbf[row*256 + col]  = xv;
      *(s4v*)&posb[row*256 + col] = pv;
      *(s4v*)&q[row*256 + col]    = qv;
    }
  }
}

// LDS-tiled weight transpose+convert to bf16 [N][K] (64x64 tiles).
// Blocks [0,1104): transpose tiles; [1104,1110): biasOA copy per layer.
__global__ __launch_bounds__(256) void convw_kernel(
    const float* __restrict__ Woff, const float* __restrict__ Waw,
    const float* __restrict__ Wv, const float* __restrict__ Wout,
    const float* __restrict__ W1, const float* __restrict__ W2,
    const float* __restrict__ boff, const float* __restrict__ baw,
    short* __restrict__ wts, float* __restrict__ biasOA)
{
  const int id = blockIdx.x;
  if (id >= 1104){
    int li = id - 1104;
    for (int i = threadIdx.x; i < 384; i += 256)
      biasOA[li*384 + i] = (i < 256) ? boff[li*256 + i] : baw[li*128 + (i-256)];
    return;
  }
  __shared__ float ls[64][65];
  const int li = id / 184;
  int r = id % 184;
  const float* src; short* dst; int N, K;
  if (r < 16)      {          src=Woff+li*65536;  dst=wts+(size_t)li*WSTRIDE;        N=256;  K=256;  }
  else if (r < 24) { r-=16;   src=Waw +li*32768;  dst=wts+(size_t)li*WSTRIDE+65536;  N=128;  K=256;  }
  else if (r < 40) { r-=24;   src=Wv  +li*65536;  dst=wts+(size_t)li*WSTRIDE+98304;  N=256;  K=256;  }
  else if (r < 56) { r-=40;   src=Wout+li*65536;  dst=wts+(size_t)li*WSTRIDE+163840; N=256;  K=256;  }
  else if (r < 120){ r-=56;   src=W1  +li*262144; dst=wts+(size_t)li*WSTRIDE+229376; N=1024; K=256;  }
  else             { r-=120;  src=W2  +li*262144; dst=wts+(size_t)li*WSTRIDE+491520; N=256;  K=1024; }
  const int ntn = N >> 6;
  const int tn = r % ntn, tk = r / ntn;
  const int n0 = tn*64, k0 = tk*64;
  const int t = threadIdx.x;
  const int rr = t >> 4;
  const int c4 = (t & 15) * 4;
  #pragma unroll
  for (int it = 0; it < 4; it++){
    int row = it*16 + rr;
    f4v v = *(const f4v*)&src[(long)(k0+row)*N + n0 + c4];
    ls[row][c4] = v[0]; ls[row][c4+1] = v[1]; ls[row][c4+2] = v[2]; ls[row][c4+3] = v[3];
  }
  __syncthreads();
  #pragma unroll
  for (int it = 0; it < 4; it++){
    int nrow = it*16 + rr;
    s4v o;
    #pragma unroll
    for (int j=0;j<4;j++) o[j] = f2bf(ls[c4+j][nrow]);
    *(s4v*)&dst[(long)(n0+nrow)*K + k0 + c4] = o;
  }
}

// Generic GEMM: C[M,N] = A*Wt^T + bias (+relu) -> f32 or bf16.
// 1-D grid, bijective XCD chunking. EMIT_Q: also q = bf16(v+pos_bf16).
template<bool RELU, bool OUT_BF16, bool EMIT_Q>
__global__ __launch_bounds__(256) void gemm_bf16(
    const short* __restrict__ A, const short* __restrict__ Wt,
    const float* __restrict__ bias,
    void* __restrict__ Cout, const short* __restrict__ posb,
    short* __restrict__ qout,
    int M, int N, int K, int NT)
{
  __shared__ short As[128*64];
  __shared__ short Bs[128*64];
  const int p = blockIdx.x, nwg = gridDim.x;
  const int xq = nwg >> 3, xr = nwg & 7;
  const int xx = p & 7, xs2 = p >> 3;
  const int l = ((xx < xr) ? xx*(xq+1) : xr*(xq+1) + (xx-xr)*xq) + xs2;
  const int m0 = (l / NT) * 128;
  const int n0 = (l % NT) * 128;

  const int t = threadIdx.x;
  const int lane = t & 63, wv = t >> 6;
  const int wm = (wv >> 1) * 64, wn = (wv & 1) * 64;
  const int fr = lane & 15, fg = lane >> 4;
  const int srow = lane >> 3;
  const int schunk = (lane & 7) ^ (srow & 7);

  f4v acc[4][4];
  #pragma unroll
  for (int i=0;i<4;i++)
    #pragma unroll
    for (int j=0;j<4;j++) acc[i][j] = (f4v){0.f,0.f,0.f,0.f};

  for (int k0 = 0; k0 < K; k0 += 64) {
    __syncthreads();
    #pragma unroll
    for (int i=0;i<4;i++){
      int seg = wv*4 + i;
      int row = seg*8 + srow;
      gload_lds16(&A [(long)(m0+row)*K + k0 + schunk*8], &As[seg*512]);
      gload_lds16(&Wt[(long)(n0+row)*K + k0 + schunk*8], &Bs[seg*512]);
    }
    __syncthreads();
    #pragma unroll
    for (int kk=0; kk<64; kk+=32){
      s8v ar[4], br[4];
      #pragma unroll
      for (int i=0;i<4;i++){
        int r = wm + i*16 + fr;
        int ch = ((kk>>3) + fg) ^ (fr & 7);
        ar[i] = *(const s8v*)&As[r*64 + ch*8];
      }
      #pragma unroll
      for (int j=0;j<4;j++){
        int r = wn + j*16 + fr;
        int ch = ((kk>>3) + fg) ^ (fr & 7);
        br[j] = *(const s8v*)&Bs[r*64 + ch*8];
      }
      #pragma unroll
      for (int i=0;i<4;i++)
        #pragma unroll
        for (int j=0;j<4;j++)
          acc[i][j] = __builtin_amdgcn_mfma_f32_16x16x32_bf16(ar[i], br[j], acc[i][j], 0,0,0);
    }
  }
  #pragma unroll
  for (int i=0;i<4;i++){
    #pragma unroll
    for (int j=0;j<4;j++){
      int col = n0 + wn + j*16 + fr;
      float bcol = bias[col];
      #pragma unroll
      for (int r=0;r<4;r++){
        long row = m0 + wm + i*16 + fg*4 + r;
        float vv = acc[i][j][r] + bcol;
        if (RELU) vv = fmaxf(vv, 0.f);
        if (OUT_BF16) ((short*)Cout)[row*N + col] = f2bf(vv);
        else ((float*)Cout)[row*N + col] = vv;
        if (EMIT_Q){
          qout[row*N + col] = f2bf(vv + bf2f(posb[row*N + col]));
        }
      }
    }
  }
}

// Fused out-proj + residual(bf16) + LayerNorm. Tile 128 rows x 256 cols.
__global__ __launch_bounds__(512) void gemm_out_ln(
    const short* __restrict__ A, const short* __restrict__ Wt,
    const float* __restrict__ bias, const short* __restrict__ resid,
    const float* __restrict__ gamma, const float* __restrict__ beta,
    short* __restrict__ xln)
{
  const int K = 256;
  __shared__ short As[128*64];
  __shared__ short Bs[256*64];
  const int m0 = blockIdx.x * 128;
  const int t = threadIdx.x;
  const int lane = t & 63, wv = t >> 6;       // 8 waves
  const int wm = wv * 16;
  const int fr = lane & 15, fg = lane >> 4;
  const int srow = lane >> 3;
  const int schunk = (lane & 7) ^ (srow & 7);

  f4v acc[16];
  #pragma unroll
  for (int j=0;j<16;j++) acc[j] = (f4v){0.f,0.f,0.f,0.f};

  for (int k0 = 0; k0 < K; k0 += 64) {
    __syncthreads();
    #pragma unroll
    for (int i=0;i<2;i++){
      int seg = wv*2 + i;
      int row = seg*8 + srow;
      gload_lds16(&A[(long)(m0+row)*K + k0 + schunk*8], &As[seg*512]);
    }
    #pragma unroll
    for (int i=0;i<4;i++){
      int seg = wv*4 + i;
      int row = seg*8 + srow;
      gload_lds16(&Wt[(long)row*K + k0 + schunk*8], &Bs[seg*512]);
    }
    __syncthreads();
    #pragma unroll
    for (int kk=0; kk<64; kk+=32){
      int ch = ((kk>>3) + fg);
      s8v ar = *(const s8v*)&As[(wm + fr)*64 + ((ch ^ (fr & 7)))*8];
      #pragma unroll
      for (int j=0;j<16;j++){
        s8v br = *(const s8v*)&Bs[(j*16 + fr)*64 + ((ch ^ (fr & 7)))*8];
        acc[j] = __builtin_amdgcn_mfma_f32_16x16x32_bf16(ar, br, acc[j], 0,0,0);
      }
    }
  }
  #pragma unroll
  for (int r=0;r<4;r++){
    long row = m0 + wm + fg*4 + r;
    float vals[16];
    float s = 0.f;
    #pragma unroll
    for (int j=0;j<16;j++){
      int col = j*16 + fr;
      float vv = acc[j][r] + bias[col] + bf2f(resid[row*256 + col]);
      vals[j] = vv; s += vv;
    }
    #pragma unroll
    for (int o=1;o<16;o<<=1) s += __shfl_xor(s, o, 64);
    float mu = s * (1.f/256.f);
    float s2 = 0.f;
    #pragma unroll
    for (int j=0;j<16;j++){ float d = vals[j]-mu; vals[j] = d; s2 += d*d; }
    #pragma unroll
    for (int o=1;o<16;o<<=1) s2 += __shfl_xor(s2, o, 64);
    float rstd = rsqrtf(s2*(1.f/256.f) + 1e-5f);
    #pragma unroll
    for (int j=0;j<16;j++){
      int col = j*16 + fr;
      xln[row*256 + col] = f2bf(vals[j]*rstd*gamma[col] + beta[col]);
    }
  }
}

// Deformable sampling — r24-exact form (84.2 µs best measured: scalar acc[8],
// VGPR 108 = deep per-thread MLP at 4 waves/SIMD; r25's f2v/VGPR-36/occ-52%
// variant measured the same 85 µs with worse FETCH -> latency equilibrium,
// micro-tuning exhausted).
__global__ __launch_bounds__(256) void sample_kernel(const short* __restrict__ v,
                const short* __restrict__ offaw, short* __restrict__ accO)
{
  const int t = threadIdx.x;
  const int qi = t >> 5;
  const int tq = t & 31;
  const int head = tq >> 2, cg = tq & 3;
  const int bid = blockIdx.x;
  const int n = ((bid & 7) * 340 + (bid >> 3)) * 8 + qi;   // XCD swizzle
  const int b = blockIdx.y;
  const long m = (long)b*LEN + n;
  const short* oa = offaw + m*384;

  s8v or0 = *(const s8v*)&oa[head*32];
  s8v or1 = *(const s8v*)&oa[head*32 + 8];
  s8v or2 = *(const s8v*)&oa[head*32 + 16];
  s8v or3 = *(const s8v*)&oa[head*32 + 24];
  float off_f[32];
  #pragma unroll
  for (int i=0;i<8;i++){
    off_f[i]    = bf2f(or0[i]);
    off_f[8+i]  = bf2f(or1[i]);
    off_f[16+i] = bf2f(or2[i]);
    off_f[24+i] = bf2f(or3[i]);
  }

  s8v lg0 = *(const s8v*)&oa[256 + head*16];
  s8v lg1 = *(const s8v*)&oa[256 + head*16 + 8];
  float logit[16];
  #pragma unroll
  for (int i=0;i<8;i++){ logit[i] = bf2f(lg0[i]); logit[8+i] = bf2f(lg1[i]); }
  float mx = -1e30f;
  #pragma unroll
  for (int j=0;j<16;j++) mx = fmaxf(mx, logit[j]);
  float ssum = 0.f;
  #pragma unroll
  for (int j=0;j<16;j++){ logit[j] = __expf(logit[j]-mx); ssum += logit[j]; }
  float inv = 1.f/ssum;

  int s0n, lwn;
  if (n < 16384){ s0n=0; lwn=7; }
  else if (n < 20480){ s0n=16384; lwn=6; }
  else if (n < 21504){ s0n=20480; lwn=5; }
  else { s0n=21504; lwn=4; }
  int p = n - s0n;
  int Wn = 1 << lwn;
  float refx = ((p & (Wn-1)) + 0.5f) / Wn;
  float refy = ((p >> lwn) + 0.5f) / Wn;

  const int starts[4] = {0,16384,20480,21504};
  float acc[8];
  #pragma unroll
  for (int c=0;c<8;c++) acc[c] = 0.f;

  #pragma unroll
  for (int l=0;l<4;l++){
    const int W = 128 >> l, Wm1 = W - 1;
    const short* vb = v + ((long)b*LEN + starts[l])*256 + head*32 + cg*8;
    #pragma unroll
    for (int pp=0;pp<4;pp++){
      int j = l*4 + pp;
      float sx = refx * W + off_f[j*2]     - 0.5f;
      float sy = refy * W + off_f[j*2 + 1] - 0.5f;
      float fx0 = floorf(sx), fy0 = floorf(sy);
      float dx = sx - fx0, dy = sy - fy0;
      int x0 = (int)fx0, y0 = (int)fy0;
      int x0c = min(max(x0,0),Wm1),   x1c = min(max(x0+1,0),Wm1);
      int y0c = min(max(y0,0),Wm1),   y1c = min(max(y0+1,0),Wm1);
      float aw = logit[j] * inv;
      float r0w = ((unsigned)y0     < (unsigned)W) ? (1.f-dy)*aw : 0.f;
      float r1w = ((unsigned)(y0+1) < (unsigned)W) ? dy*aw       : 0.f;
      float c0w = ((unsigned)x0     < (unsigned)W) ? (1.f-dx)    : 0.f;
      float c1w = ((unsigned)(x0+1) < (unsigned)W) ? dx          : 0.f;
      float w00 = r0w*c0w, w10 = r0w*c1w, w01 = r1w*c0w, w11 = r1w*c1w;
      const short* r0p = vb + (long)(y0c*W)*256;
      const short* r1p = vb + (long)(y1c*W)*256;
      u4v g00 = *(const u4v*)&r0p[x0c*256];
      u4v g10 = *(const u4v*)&r0p[x1c*256];
      u4v g01 = *(const u4v*)&r1p[x0c*256];
      u4v g11 = *(const u4v*)&r1p[x1c*256];
      #pragma unroll
      for (int c=0;c<4;c++){
        union {unsigned u; float f;} lo00,hi00,lo10,hi10,lo01,hi01,lo11,hi11;
        lo00.u = g00[c] << 16;  hi00.u = g00[c];
        lo10.u = g10[c] << 16;  hi10.u = g10[c];
        lo01.u = g01[c] << 16;  hi01.u = g01[c];
        lo11.u = g11[c] << 16;  hi11.u = g11[c];
        acc[2*c]   += w00*lo00.f + w10*lo10.f + w01*lo01.f + w11*lo11.f;
        acc[2*c+1] += w00*hi00.f + w10*hi10.f + w01*hi01.f + w11*hi11.f;
      }
    }
  }
  s8v o;
  #pragma unroll
  for (int c=0;c<8;c++) o[c] = f2bf(acc[c]);
  *(s8v*)&accO[m*256 + head*32 + cg*8] = o;
}

extern "C" void kernel_launch(void* const* d_in, const int* in_sizes, int n_in,
                              void* d_out, int out_size, void* d_ws, size_t ws_size,
                              hipStream_t stream)
{
  const float* s0   = (const float*)d_in[0];
  const float* p0   = (const float*)d_in[1];
  const float* s1   = (const float*)d_in[2];
  const float* p1   = (const float*)d_in[3];
  const float* s2   = (const float*)d_in[4];
  const float* p2   = (const float*)d_in[5];
  const float* s3   = (const float*)d_in[6];
  const float* p3   = (const float*)d_in[7];
  const float* le   = (const float*)d_in[8];
  const float* Wv   = (const float*)d_in[9];
  const float* bv   = (const float*)d_in[10];
  const float* Woff = (const float*)d_in[11];
  const float* boff = (const float*)d_in[12];
  const float* Waw  = (const float*)d_in[13];
  const float* baw  = (const float*)d_in[14];
  const float* Wout = (const float*)d_in[15];
  const float* bout = (const float*)d_in[16];
  const float* gamma= (const float*)d_in[17];
  const float* beta = (const float*)d_in[18];
  const float* W1   = (const float*)d_in[19];
  const float* b1   = (const float*)d_in[20];
  const float* W2   = (const float*)d_in[21];
  const float* b2   = (const float*)d_in[22];

  char* wsb = (char*)d_ws;
  short* xbf   = (short*)(wsb);                // 22,282,240 (bf16 residual stream)
  short* posb  = (short*)(wsb + 22282240);     // 22,282,240 (bf16 pos)
  short* qxln  = (short*)(wsb + 44564480);     // 22,282,240 (q | xln)
  // scratch region R (89,128,960 B): attention {vbf, accb, offaw} | FFN {h}
  short* vbf   = (short*)(wsb + 66846720);     // 22,282,240
  short* accb  = (short*)(wsb + 89128960);     // 22,282,240
  short* offawh= (short*)(wsb + 111411200);    // 33,423,360 used (offaw)
  short* hbuf  = (short*)(wsb + 66846720);     // 89,128,960 (FFN hidden, aliases above)
  short* wts   = (short*)(wsb + 155975680);    // 9,043,968
  float* biasOA= (float*)(wsb + 165019648);    // 9,216

  prep_kernel<<<dim3(340,2),256,0,stream>>>(s0,s1,s2,s3,p0,p1,p2,p3,le,xbf,posb,qxln);
  convw_kernel<<<1110,256,0,stream>>>(Woff,Waw,Wv,Wout,W1,W2,boff,baw,wts,biasOA);

  for (int li = 0; li < 6; li++){
    const short* wl = wts + (size_t)li*WSTRIDE;
    // offsets + attention logits: [M,384]  (reads q in qxln); 340x3 tiles
    gemm_bf16<false,true,false><<<1020,256,0,stream>>>(
        qxln, wl, biasOA+li*384, offawh, nullptr,nullptr, MROWS, 384, 256, 3);
    // values: [M,256] bf16  (reads residual stream xbf); 340x2 tiles
    gemm_bf16<false,true,false><<<680,256,0,stream>>>(
        xbf, wl+98304, bv+li*256, vbf, nullptr,nullptr, MROWS, 256, 256, 2);
    // deformable sampling -> accb
    sample_kernel<<<dim3(LEN/8,2),256,0,stream>>>(vbf, offawh, accb);
    // fused out-proj + residual(bf16 xbf) + LN -> xln (qxln)
    gemm_out_ln<<<340,512,0,stream>>>(accb, wl+163840, bout+li*256, xbf,
                                      gamma+li*256, beta+li*256, qxln);
    // FFN, unchunked: FFN1 writes h (aliases dead vbf/accb/offaw), FFN2 -> xbf+q
    gemm_bf16<true,true,false><<<2720,256,0,stream>>>(
        qxln, wl+229376, b1+li*1024, hbuf, nullptr,nullptr, MROWS, 1024, 256, 8);
    if (li < 5){
      gemm_bf16<false,true,true><<<680,256,0,stream>>>(
          hbuf, wl+491520, b2+li*256, xbf, posb, qxln, MROWS, 256, 1024, 2);
    } else {
      gemm_bf16<false,false,false><<<680,256,0,stream>>>(
          hbuf, wl+491520, b2+li*256, (float*)d_out, nullptr,nullptr, MROWS, 256, 1024, 2);
    }
  }
}